// Round 10
// baseline (163.992 us; speedup 1.0000x reference)
//
#include <hip/hip_runtime.h>

// VQ-VAE quantization: two-sweep bf16-MFMA prefilter + exact fp32 rescore.
// Round 10: residency attack, done right this time. 8 waves/block x 512
// codes/wave, plain __launch_bounds__(512) (NO min-waves arg -> no VGPR
// coercion; r8's 512,8 forced 64 VGPR and spilled 2.3GB to scratch).
// VGPR ~72 -> 7 waves/SIMD cap -> 3 blocks/CU = 24 waves/CU (r9: 16).
// Sweep-2 init-fold: acc C-init = -h - thr, so push test is acc>=0 and the
// per-tile 16 subs disappear. Everything else = r9 (156us):
//   sweep1: row max (16 fmax/tile), cross-wave LDS max -> thr = max - DELTA
//   sweep2: ballot-gated push of acc>=0 candidates
//   rescore: exact fp32 distance, LDS atomicMin (ordbits<<32|code)
//            -> exact argmin, first-index ties (jnp.argmin semantics).
// DELTA=0.25 >= 2x worst bf16 dot error -> true winner always in the list.

#define NPTS    65536
#define CDIM    64
#define KCODES  4096
#define WAVES   8
#define KPW     (KCODES / WAVES)   // 512 codes per wave
#define TILES   (KPW / 16)         // 32 tiles of 16 codes
#define LISTCAP 4096
#define DELTA   0.25f

typedef __attribute__((ext_vector_type(8))) short short8;
typedef __attribute__((ext_vector_type(4))) float f32x4;

__device__ __forceinline__ unsigned short f2bf(float x) {
    unsigned u = __float_as_uint(x);
    return (unsigned short)((u + 0x7FFFu + ((u >> 16) & 1u)) >> 16);  // RNE
}

struct BT { short8 b0, b1; float hh; };

// cb fp32 -> bf16 copy + h[k] = 0.5*||e_k||^2
__global__ __launch_bounds__(256) void vq_prep(const float* __restrict__ cb,
                                               short* __restrict__ cbb,
                                               float* __restrict__ h) {
    int k = blockIdx.x * 256 + threadIdx.x;
    const float4* p = reinterpret_cast<const float4*>(cb + (size_t)k * CDIM);
    float s0 = 0.f, s1 = 0.f, s2 = 0.f, s3 = 0.f;
#pragma unroll
    for (int i = 0; i < 16; i += 2) {
        float4 va = p[i], vb = p[i + 1];
        s0 = fmaf(va.x, va.x, s0); s1 = fmaf(va.y, va.y, s1);
        s2 = fmaf(va.z, va.z, s2); s3 = fmaf(va.w, va.w, s3);
        s0 = fmaf(vb.x, vb.x, s0); s1 = fmaf(vb.y, vb.y, s1);
        s2 = fmaf(vb.z, vb.z, s2); s3 = fmaf(vb.w, vb.w, s3);
        short8 o;
        o[0] = (short)f2bf(va.x); o[1] = (short)f2bf(va.y);
        o[2] = (short)f2bf(va.z); o[3] = (short)f2bf(va.w);
        o[4] = (short)f2bf(vb.x); o[5] = (short)f2bf(vb.y);
        o[6] = (short)f2bf(vb.z); o[7] = (short)f2bf(vb.w);
        *reinterpret_cast<short8*>(cbb + (size_t)k * CDIM + i * 4) = o;
    }
    h[k] = 0.5f * ((s0 + s1) + (s2 + s3));
}

__global__ __launch_bounds__(512) void vq_main(const float* __restrict__ enc,
                                               const float* __restrict__ cbf,
                                               const short* __restrict__ cbb,
                                               const float* __restrict__ h,
                                               float* __restrict__ out) {
    __shared__ unsigned list[LISTCAP];
    __shared__ float rowmax[WAVES][64];
    __shared__ float thrL[64];
    __shared__ unsigned long long mkey[64];
    __shared__ unsigned lcnt;

    const int tid  = threadIdx.x;
    const int wid  = tid >> 6, lane = tid & 63;
    const int lrow = lane & 15, lseg = lane >> 4;
    const int pbase = blockIdx.x * 64;     // 64 points per block
    const int k0 = wid * KPW;              // this wave's 512-code slice

    if (tid == 0) lcnt = 0;
    if (tid < 64) mkey[tid] = ~0ull;

    // ---- A fragments: the block's 64 points as bf16 (all waves identical) ----
    // 16x16x32 A layout: row = lane&15, k = (lane>>4)*8 + e (+32 per kk)
    short8 afr[4][2];
#pragma unroll
    for (int rt = 0; rt < 4; ++rt)
#pragma unroll
        for (int kk = 0; kk < 2; ++kk) {
            const float4* xp = reinterpret_cast<const float4*>(
                enc + (size_t)(pbase + rt * 16 + lrow) * CDIM + kk * 32 + lseg * 8);
            float4 v0 = xp[0], v1 = xp[1];
            short8 a;
            a[0] = (short)f2bf(v0.x); a[1] = (short)f2bf(v0.y);
            a[2] = (short)f2bf(v0.z); a[3] = (short)f2bf(v0.w);
            a[4] = (short)f2bf(v1.x); a[5] = (short)f2bf(v1.y);
            a[6] = (short)f2bf(v1.z); a[7] = (short)f2bf(v1.w);
            afr[rt][kk] = a;
        }
    __syncthreads();   // lcnt/mkey init visible before any push

    auto loadB = [&](int ct, BT& s) {
        int code = k0 + ct * 16 + lrow;
        const short* base = cbb + (size_t)code * CDIM + lseg * 8;
        s.b0 = *reinterpret_cast<const short8*>(base);
        s.b1 = *reinterpret_cast<const short8*>(base + 32);
        s.hh = h[code];
    };

    // ---- sweep 1: pure row-max, depth-4 prefetch (static slots) ----
    f32x4 best[4];
#pragma unroll
    for (int rt = 0; rt < 4; ++rt)
#pragma unroll
        for (int i = 0; i < 4; ++i) best[rt][i] = -__builtin_inff();

    {
        BT s0, s1, s2, s3;
        loadB(0, s0); loadB(1, s1); loadB(2, s2); loadB(3, s3);
#define S1BODY(SLOT, T)                                                        \
        {                                                                      \
            float nh = -SLOT.hh;                                               \
            f32x4 acc[4];                                                      \
            _Pragma("unroll")                                                  \
            for (int rt = 0; rt < 4; ++rt) {                                   \
                acc[rt][0] = nh; acc[rt][1] = nh;                              \
                acc[rt][2] = nh; acc[rt][3] = nh;                              \
            }                                                                  \
            _Pragma("unroll")                                                  \
            for (int rt = 0; rt < 4; ++rt)                                     \
                acc[rt] = __builtin_amdgcn_mfma_f32_16x16x32_bf16(afr[rt][0], SLOT.b0, acc[rt], 0, 0, 0); \
            _Pragma("unroll")                                                  \
            for (int rt = 0; rt < 4; ++rt)                                     \
                acc[rt] = __builtin_amdgcn_mfma_f32_16x16x32_bf16(afr[rt][1], SLOT.b1, acc[rt], 0, 0, 0); \
            _Pragma("unroll")                                                  \
            for (int rt = 0; rt < 4; ++rt)                                     \
                _Pragma("unroll")                                              \
                for (int i = 0; i < 4; ++i)                                    \
                    best[rt][i] = fmaxf(best[rt][i], acc[rt][i]);              \
            loadB((T) + 4 < TILES ? (T) + 4 : 0, SLOT);                        \
        }
        for (int t = 0; t < TILES; t += 4) {
            S1BODY(s0, t + 0)
            S1BODY(s1, t + 1)
            S1BODY(s2, t + 2)
            S1BODY(s3, t + 3)
        }
#undef S1BODY
    }

    // intra-wave max over the 16 col-lanes
#pragma unroll
    for (int m = 1; m <= 8; m <<= 1)
#pragma unroll
        for (int rt = 0; rt < 4; ++rt)
#pragma unroll
            for (int i = 0; i < 4; ++i)
                best[rt][i] = fmaxf(best[rt][i], __shfl_xor(best[rt][i], m, 64));
    if (lrow == 0) {   // lanes 0,16,32,48 cover all 64 rows
#pragma unroll
        for (int rt = 0; rt < 4; ++rt)
#pragma unroll
            for (int i = 0; i < 4; ++i)
                rowmax[wid][rt * 16 + lseg * 4 + i] = best[rt][i];
    }
    __syncthreads();
    if (tid < 64) {    // global row max across the 8 waves -> threshold
        float m0 = fmaxf(rowmax[0][tid], rowmax[1][tid]);
        float m1 = fmaxf(rowmax[2][tid], rowmax[3][tid]);
        float m2 = fmaxf(rowmax[4][tid], rowmax[5][tid]);
        float m3 = fmaxf(rowmax[6][tid], rowmax[7][tid]);
        thrL[tid] = fmaxf(fmaxf(m0, m1), fmaxf(m2, m3)) - DELTA;
    }
    __syncthreads();

    f32x4 thr[4];
#pragma unroll
    for (int rt = 0; rt < 4; ++rt)
#pragma unroll
        for (int i = 0; i < 4; ++i) thr[rt][i] = thrL[rt * 16 + lseg * 4 + i];

    // ---- sweep 2: C-init = -h - thr, so test is acc >= 0; ballot gate ----
    {
        BT s0, s1, s2, s3;
        loadB(0, s0); loadB(1, s1); loadB(2, s2); loadB(3, s3);
#define S2BODY(SLOT, T)                                                        \
        {                                                                      \
            float nh = -SLOT.hh;                                               \
            f32x4 acc[4];                                                      \
            _Pragma("unroll")                                                  \
            for (int rt = 0; rt < 4; ++rt)                                     \
                _Pragma("unroll")                                              \
                for (int i = 0; i < 4; ++i)                                    \
                    acc[rt][i] = nh - thr[rt][i];                              \
            _Pragma("unroll")                                                  \
            for (int rt = 0; rt < 4; ++rt)                                     \
                acc[rt] = __builtin_amdgcn_mfma_f32_16x16x32_bf16(afr[rt][0], SLOT.b0, acc[rt], 0, 0, 0); \
            _Pragma("unroll")                                                  \
            for (int rt = 0; rt < 4; ++rt)                                     \
                acc[rt] = __builtin_amdgcn_mfma_f32_16x16x32_bf16(afr[rt][1], SLOT.b1, acc[rt], 0, 0, 0); \
            float g0 = fmaxf(fmaxf(fmaxf(acc[0][0], acc[0][1]), fmaxf(acc[0][2], acc[0][3])),  \
                             fmaxf(fmaxf(acc[1][0], acc[1][1]), fmaxf(acc[1][2], acc[1][3]))); \
            float g1 = fmaxf(fmaxf(fmaxf(acc[2][0], acc[2][1]), fmaxf(acc[2][2], acc[2][3])),  \
                             fmaxf(fmaxf(acc[3][0], acc[3][1]), fmaxf(acc[3][2], acc[3][3]))); \
            if (__ballot(fmaxf(g0, g1) >= 0.f)) {                              \
                unsigned code = (unsigned)(k0 + (T) * 16 + lrow);              \
                _Pragma("unroll")                                              \
                for (int rt = 0; rt < 4; ++rt)                                 \
                    _Pragma("unroll")                                          \
                    for (int i = 0; i < 4; ++i)                                \
                        if (acc[rt][i] >= 0.f) {                               \
                            unsigned row = (unsigned)(rt * 16 + lseg * 4 + i); /* C/D row map (m89) */ \
                            unsigned pos = atomicAdd(&lcnt, 1u);               \
                            if (pos < LISTCAP) list[pos] = (row << 12) | code; \
                        }                                                      \
            }                                                                  \
            loadB((T) + 4 < TILES ? (T) + 4 : 0, SLOT);                        \
        }
        for (int t = 0; t < TILES; t += 4) {
            S2BODY(s0, t + 0)
            S2BODY(s1, t + 1)
            S2BODY(s2, t + 2)
            S2BODY(s3, t + 3)
        }
#undef S2BODY
    }
    __syncthreads();

    // ---- exact fp32 rescore: 4 lanes per candidate (coalesced 256B) ----
    unsigned cnt = lcnt; if (cnt > LISTCAP) cnt = LISTCAP;
    for (unsigned t4 = tid; t4 < cnt * 4; t4 += 512) {
        unsigned t = t4 >> 2; int q = t4 & 3;
        unsigned e = list[t];
        int row = (int)(e >> 12), c = (int)(e & 4095u);
        const float4* xp = reinterpret_cast<const float4*>(enc + (size_t)(pbase + row) * CDIM) + q * 4;
        const float4* ep = reinterpret_cast<const float4*>(cbf + (size_t)c * CDIM) + q * 4;
        float a0 = 0.f, a1 = 0.f, a2 = 0.f, a3 = 0.f;
#pragma unroll
        for (int i = 0; i < 4; ++i) {
            float4 xv = xp[i], ev = ep[i];
            a0 = fmaf(xv.x, ev.x, a0); a1 = fmaf(xv.y, ev.y, a1);
            a2 = fmaf(xv.z, ev.z, a2); a3 = fmaf(xv.w, ev.w, a3);
        }
        float p = (a0 + a1) + (a2 + a3);
        p += __shfl_xor(p, 1, 64);
        p += __shfl_xor(p, 2, 64);               // full dot in all 4 lanes
        if (q == 0) {
            float d2 = fmaf(-2.f, p, 2.f * h[c]);     // esq - 2*dot (bit-identical everywhere)
            unsigned bb = __float_as_uint(d2);
            unsigned ord = bb ^ (unsigned)(((int)bb >> 31) | 0x80000000);  // monotonic
            atomicMin(&mkey[row], ((unsigned long long)ord << 32) | (unsigned)c);
        }
    }
    __syncthreads();

    // ---- finalize: gather winner rows (8 threads per point) + idx ----
    {
        int p = tid >> 3, q = tid & 7;
        int c = (int)(mkey[p] & 4095u);
        const float4* ep = reinterpret_cast<const float4*>(cbf + (size_t)c * CDIM);
        float4* op = reinterpret_cast<float4*>(out + (size_t)(pbase + p) * CDIM);
        op[q] = ep[q];
        op[q + 8] = ep[q + 8];
        if (tid < 64)
            out[(size_t)NPTS * CDIM + pbase + tid] = (float)(mkey[tid] & 4095u);
    }
}

extern "C" void kernel_launch(void* const* d_in, const int* in_sizes, int n_in,
                              void* d_out, int out_size, void* d_ws, size_t ws_size,
                              hipStream_t stream) {
    const float* enc = (const float*)d_in[0];
    const float* cb  = (const float*)d_in[1];
    float* out = (float*)d_out;

    // ws: cbb bf16[4096*64] (512KB) | h fp32[4096] (16KB)
    short* cbb = (short*)d_ws;
    float* hws = (float*)(cbb + (size_t)KCODES * CDIM);

    vq_prep<<<KCODES / 256, 256, 0, stream>>>(cb, cbb, hws);
    vq_main<<<NPTS / 64, 512, 0, stream>>>(enc, cb, cbb, hws, out);
}

// Round 11
// 155.506 us; speedup vs baseline: 1.0546x; 1.0546x over previous
//
#include <hip/hip_runtime.h>

// VQ-VAE quantization: sampled-threshold bf16-MFMA prefilter + exact fp32 rescore.
// Round 11 = r9 (156us) with sweep-1 cut to a 1/8 sample: the threshold only
// needs ANY lower bound on the row max; sampledmax - DELTA still provably
// captures the true winner (s(c*) >= sampledmax - 2*eps, DELTA=0.25 >= 2*eps).
// Bodies per wave: 128 -> 72 (-44% MFMA+VALU). Extra candidates (~8/row) are
// absorbed by the exact rescore. LISTCAP doubled to 8192 for headroom.
//   sample sweep: 8 of 64 tiles (stride 8) -> per-wave row max
//                 -> cross-wave LDS max -> thr = max - DELTA
//   sweep2: full 64 tiles; ballot-gated push of acc >= thr candidates
//   rescore: exact fp32 distance (4 lanes/cand), LDS atomicMin on
//            (ordbits(dist)<<32|code) -> exact argmin, first-index ties.

#define NPTS    65536
#define CDIM    64
#define KCODES  4096
#define WAVES   4
#define KPW     (KCODES / WAVES)   // 1024 codes per wave
#define TILES   (KPW / 16)         // 64 tiles of 16 codes
#define LISTCAP 8192
#define DELTA   0.25f

typedef __attribute__((ext_vector_type(8))) short short8;
typedef __attribute__((ext_vector_type(4))) float f32x4;

__device__ __forceinline__ unsigned short f2bf(float x) {
    unsigned u = __float_as_uint(x);
    return (unsigned short)((u + 0x7FFFu + ((u >> 16) & 1u)) >> 16);  // RNE
}

struct BT { short8 b0, b1; float hh; };

// cb fp32 -> bf16 copy + h[k] = 0.5*||e_k||^2
__global__ __launch_bounds__(256) void vq_prep(const float* __restrict__ cb,
                                               short* __restrict__ cbb,
                                               float* __restrict__ h) {
    int k = blockIdx.x * 256 + threadIdx.x;
    const float4* p = reinterpret_cast<const float4*>(cb + (size_t)k * CDIM);
    float s0 = 0.f, s1 = 0.f, s2 = 0.f, s3 = 0.f;
#pragma unroll
    for (int i = 0; i < 16; i += 2) {
        float4 va = p[i], vb = p[i + 1];
        s0 = fmaf(va.x, va.x, s0); s1 = fmaf(va.y, va.y, s1);
        s2 = fmaf(va.z, va.z, s2); s3 = fmaf(va.w, va.w, s3);
        s0 = fmaf(vb.x, vb.x, s0); s1 = fmaf(vb.y, vb.y, s1);
        s2 = fmaf(vb.z, vb.z, s2); s3 = fmaf(vb.w, vb.w, s3);
        short8 o;
        o[0] = (short)f2bf(va.x); o[1] = (short)f2bf(va.y);
        o[2] = (short)f2bf(va.z); o[3] = (short)f2bf(va.w);
        o[4] = (short)f2bf(vb.x); o[5] = (short)f2bf(vb.y);
        o[6] = (short)f2bf(vb.z); o[7] = (short)f2bf(vb.w);
        *reinterpret_cast<short8*>(cbb + (size_t)k * CDIM + i * 4) = o;
    }
    h[k] = 0.5f * ((s0 + s1) + (s2 + s3));
}

__global__ __launch_bounds__(256) void vq_main(const float* __restrict__ enc,
                                               const float* __restrict__ cbf,
                                               const short* __restrict__ cbb,
                                               const float* __restrict__ h,
                                               float* __restrict__ out) {
    __shared__ unsigned list[LISTCAP];
    __shared__ float rowmax[WAVES][64];
    __shared__ float thrL[64];
    __shared__ unsigned long long mkey[64];
    __shared__ unsigned lcnt;

    const int tid  = threadIdx.x;
    const int wid  = tid >> 6, lane = tid & 63;
    const int lrow = lane & 15, lseg = lane >> 4;
    const int pbase = blockIdx.x * 64;     // 64 points per block
    const int k0 = wid * KPW;              // this wave's 1024-code slice

    if (tid == 0) lcnt = 0;
    if (tid < 64) mkey[tid] = ~0ull;

    // ---- A fragments: the block's 64 points as bf16 ----
    // 16x16x32 A layout: row = lane&15, k = (lane>>4)*8 + e (+32 per kk)
    short8 afr[4][2];
#pragma unroll
    for (int rt = 0; rt < 4; ++rt)
#pragma unroll
        for (int kk = 0; kk < 2; ++kk) {
            const float4* xp = reinterpret_cast<const float4*>(
                enc + (size_t)(pbase + rt * 16 + lrow) * CDIM + kk * 32 + lseg * 8);
            float4 v0 = xp[0], v1 = xp[1];
            short8 a;
            a[0] = (short)f2bf(v0.x); a[1] = (short)f2bf(v0.y);
            a[2] = (short)f2bf(v0.z); a[3] = (short)f2bf(v0.w);
            a[4] = (short)f2bf(v1.x); a[5] = (short)f2bf(v1.y);
            a[6] = (short)f2bf(v1.z); a[7] = (short)f2bf(v1.w);
            afr[rt][kk] = a;
        }
    __syncthreads();   // lcnt/mkey init visible before any push

    auto loadB = [&](int ct, BT& s) {
        int code = k0 + ct * 16 + lrow;
        const short* base = cbb + (size_t)code * CDIM + lseg * 8;
        s.b0 = *reinterpret_cast<const short8*>(base);
        s.b1 = *reinterpret_cast<const short8*>(base + 32);
        s.hh = h[code];
    };

    // MFMA body: acc = A.B - h (h folded into C-init)
    auto mfmaT = [&](const BT& s, f32x4* acc) {
        float nh = -s.hh;
#pragma unroll
        for (int rt = 0; rt < 4; ++rt) { acc[rt][0] = nh; acc[rt][1] = nh; acc[rt][2] = nh; acc[rt][3] = nh; }
#pragma unroll
        for (int rt = 0; rt < 4; ++rt)
            acc[rt] = __builtin_amdgcn_mfma_f32_16x16x32_bf16(afr[rt][0], s.b0, acc[rt], 0, 0, 0);
#pragma unroll
        for (int rt = 0; rt < 4; ++rt)
            acc[rt] = __builtin_amdgcn_mfma_f32_16x16x32_bf16(afr[rt][1], s.b1, acc[rt], 0, 0, 0);
    };

    // ---- sample sweep: tiles {0,8,...,56}, row max only ----
    f32x4 best[4];
#pragma unroll
    for (int rt = 0; rt < 4; ++rt)
#pragma unroll
        for (int i = 0; i < 4; ++i) best[rt][i] = -__builtin_inff();

    {
        BT s0, s1, s2, s3;
        loadB(0, s0); loadB(8, s1); loadB(16, s2); loadB(24, s3);
#define SSBODY(SLOT, J)                                                        \
        {                                                                      \
            f32x4 acc[4];                                                      \
            mfmaT(SLOT, acc);                                                  \
            _Pragma("unroll")                                                  \
            for (int rt = 0; rt < 4; ++rt)                                     \
                _Pragma("unroll")                                              \
                for (int i = 0; i < 4; ++i)                                    \
                    best[rt][i] = fmaxf(best[rt][i], acc[rt][i]);              \
            loadB((((J) + 4) & 7) * 8, SLOT);                                  \
        }
        SSBODY(s0, 0) SSBODY(s1, 1) SSBODY(s2, 2) SSBODY(s3, 3)
        SSBODY(s0, 4) SSBODY(s1, 5) SSBODY(s2, 6) SSBODY(s3, 7)
#undef SSBODY
    }

    // intra-wave max over the 16 col-lanes
#pragma unroll
    for (int m = 1; m <= 8; m <<= 1)
#pragma unroll
        for (int rt = 0; rt < 4; ++rt)
#pragma unroll
            for (int i = 0; i < 4; ++i)
                best[rt][i] = fmaxf(best[rt][i], __shfl_xor(best[rt][i], m, 64));
    if (lrow == 0) {   // lanes 0,16,32,48 cover all 64 rows
#pragma unroll
        for (int rt = 0; rt < 4; ++rt)
#pragma unroll
            for (int i = 0; i < 4; ++i)
                rowmax[wid][rt * 16 + lseg * 4 + i] = best[rt][i];
    }
    __syncthreads();
    if (tid < 64) {    // cross-wave max of sampled maxes -> threshold
        float m0 = fmaxf(rowmax[0][tid], rowmax[1][tid]);
        float m1 = fmaxf(rowmax[2][tid], rowmax[3][tid]);
        thrL[tid] = fmaxf(m0, m1) - DELTA;
    }
    __syncthreads();

    f32x4 thr[4];
#pragma unroll
    for (int rt = 0; rt < 4; ++rt)
#pragma unroll
        for (int i = 0; i < 4; ++i) thr[rt][i] = thrL[rt * 16 + lseg * 4 + i];

    // ---- sweep 2: full 64 tiles; tree-max + one ballot gate, rare push ----
    {
        BT s0, s1, s2, s3;
        loadB(0, s0); loadB(1, s1); loadB(2, s2); loadB(3, s3);
#define S2BODY(SLOT, T)                                                        \
        {                                                                      \
            f32x4 acc[4];                                                      \
            mfmaT(SLOT, acc);                                                  \
            f32x4 d[4];                                                        \
            _Pragma("unroll")                                                  \
            for (int rt = 0; rt < 4; ++rt)                                     \
                _Pragma("unroll")                                              \
                for (int i = 0; i < 4; ++i)                                    \
                    d[rt][i] = acc[rt][i] - thr[rt][i];                        \
            float g0 = fmaxf(fmaxf(fmaxf(d[0][0], d[0][1]), fmaxf(d[0][2], d[0][3])),  \
                             fmaxf(fmaxf(d[1][0], d[1][1]), fmaxf(d[1][2], d[1][3]))); \
            float g1 = fmaxf(fmaxf(fmaxf(d[2][0], d[2][1]), fmaxf(d[2][2], d[2][3])),  \
                             fmaxf(fmaxf(d[3][0], d[3][1]), fmaxf(d[3][2], d[3][3]))); \
            if (__ballot(fmaxf(g0, g1) >= 0.f)) {                              \
                unsigned code = (unsigned)(k0 + (T) * 16 + lrow);              \
                _Pragma("unroll")                                              \
                for (int rt = 0; rt < 4; ++rt)                                 \
                    _Pragma("unroll")                                          \
                    for (int i = 0; i < 4; ++i)                                \
                        if (d[rt][i] >= 0.f) {                                 \
                            unsigned row = (unsigned)(rt * 16 + lseg * 4 + i); /* C/D map (m89) */ \
                            unsigned pos = atomicAdd(&lcnt, 1u);               \
                            if (pos < LISTCAP) list[pos] = (row << 12) | code; \
                        }                                                      \
            }                                                                  \
            loadB(((T) + 4) & (TILES - 1), SLOT);                              \
        }
        for (int t = 0; t < TILES; t += 4) {
            S2BODY(s0, t + 0)
            S2BODY(s1, t + 1)
            S2BODY(s2, t + 2)
            S2BODY(s3, t + 3)
        }
#undef S2BODY
    }
    __syncthreads();

    // ---- exact fp32 rescore: 4 lanes per candidate (coalesced 256B) ----
    unsigned cnt = lcnt; if (cnt > LISTCAP) cnt = LISTCAP;
    for (unsigned t4 = tid; t4 < cnt * 4; t4 += 256) {
        unsigned t = t4 >> 2; int q = t4 & 3;
        unsigned e = list[t];
        int row = (int)(e >> 12), c = (int)(e & 4095u);
        const float4* xp = reinterpret_cast<const float4*>(enc + (size_t)(pbase + row) * CDIM) + q * 4;
        const float4* ep = reinterpret_cast<const float4*>(cbf + (size_t)c * CDIM) + q * 4;
        float a0 = 0.f, a1 = 0.f, a2 = 0.f, a3 = 0.f;
#pragma unroll
        for (int i = 0; i < 4; ++i) {
            float4 xv = xp[i], ev = ep[i];
            a0 = fmaf(xv.x, ev.x, a0); a1 = fmaf(xv.y, ev.y, a1);
            a2 = fmaf(xv.z, ev.z, a2); a3 = fmaf(xv.w, ev.w, a3);
        }
        float p = (a0 + a1) + (a2 + a3);
        p += __shfl_xor(p, 1, 64);
        p += __shfl_xor(p, 2, 64);               // full dot in all 4 lanes
        if (q == 0) {
            float d2 = fmaf(-2.f, p, 2.f * h[c]);     // esq - 2*dot (bit-identical everywhere)
            unsigned bb = __float_as_uint(d2);
            unsigned ord = bb ^ (unsigned)(((int)bb >> 31) | 0x80000000);  // monotonic
            atomicMin(&mkey[row], ((unsigned long long)ord << 32) | (unsigned)c);
        }
    }
    __syncthreads();

    // ---- finalize: gather winner rows (4 threads per point) + idx ----
    {
        int p = tid >> 2, q = tid & 3;
        int c = (int)(mkey[p] & 4095u);
        const float4* ep = reinterpret_cast<const float4*>(cbf + (size_t)c * CDIM) + q * 4;
        float4* op = reinterpret_cast<float4*>(out + (size_t)(pbase + p) * CDIM) + q * 4;
#pragma unroll
        for (int i = 0; i < 4; ++i) op[i] = ep[i];
        if (tid < 64)
            out[(size_t)NPTS * CDIM + pbase + tid] = (float)(mkey[tid] & 4095u);
    }
}

extern "C" void kernel_launch(void* const* d_in, const int* in_sizes, int n_in,
                              void* d_out, int out_size, void* d_ws, size_t ws_size,
                              hipStream_t stream) {
    const float* enc = (const float*)d_in[0];
    const float* cb  = (const float*)d_in[1];
    float* out = (float*)d_out;

    // ws: cbb bf16[4096*64] (512KB) | h fp32[4096] (16KB)
    short* cbb = (short*)d_ws;
    float* hws = (float*)(cbb + (size_t)KCODES * CDIM);

    vq_prep<<<KCODES / 256, 256, 0, stream>>>(cb, cbb, hws);
    vq_main<<<NPTS / 64, 256, 0, stream>>>(enc, cb, cbb, hws, out);
}